// Round 8
// baseline (526.495 us; speedup 1.0000x reference)
//
#include <hip/hip_runtime.h>
#include <hip/hip_cooperative_groups.h>

namespace cg = cooperative_groups;

// A3TGCN collapses (TGCN hidden state is None -> zeros every period) to:
//   agg = D^-1/2 (A + I) D^-1/2 X            [N,12]  (GCN aggregation)
//   Z[n,p,k]  = sigmoid(agg[n,p]*az[k] + bz[k])      az = conv_w_z @ lin_w_z[:128]
//   Ht[n,p,k] = tanh   (agg[n,p]*ah[k] + bh[k])
//   h[n,k]    = sum_p softmax(att)[p] * (1-Z)*Ht
//   out       = elu(h) @ W_out + b_out        [N,12]
// R-branch (d_in[8..11]) provably unused: H_state==0 so R gates nothing.
// Dtypes: float32 tensors + int32 indices (verified R2-R6, absmax 7.6e-6).
//
// R7 -> R8: R7's cooperative launch silently failed (output all zeros = kernel
// never ran; hard-coded 1024 blocks likely exceeded runtime occupancy ->
// hipErrorCooperativeLaunchTooLarge, return code unchecked). Now: grid sized
// from hipOccupancyMaxActiveBlocksPerMultiprocessor (host query, capture-safe),
// launch_bounds relaxed to (256,2), return code CHECKED with fallback to the
// proven R6 multi-kernel bucket pipeline in the same call.

#define PP 12
#define HH 128
#define OO 12
#define CAP 96
#define NTHR 256

__device__ __forceinline__ float fast_rcp(float x) { return __builtin_amdgcn_rcpf(x); }
__device__ __forceinline__ float fast_rsq(float x) { return __builtin_amdgcn_rsqf(x); }

struct Params {
    const float* x; const int* srcv; const int* dstv; const float* ew;
    const float* att;
    const float* cwz; const float* cbz; const float* Wz; const float* lbz;
    const float* cwh; const float* cbh; const float* Wh; const float* lbh;
    const float* Wout; const float* bout;
    float* out;
    int2* bucket; int* cursor; float* dinv; float* y;
    float* az; float* bz; float* ah; float* bh; float* probs;
    int N; int E;
};

// ---- shared device bodies ----

__device__ __forceinline__ void fold_task(const Params& p, int task, int lane) {
    // tasks 0..511: one wave per folded coefficient; task 512: softmax(att)
    if (task < 512) {
        int prm = task >> 7, k = task & 127;
        const float* cw = (prm == 0) ? p.cwz : (prm == 1) ? p.cbz : (prm == 2) ? p.cwh : p.cbh;
        const float* W  = (prm < 2) ? p.Wz : p.Wh;   // lin_w is (256,128); rows 0..127 used
        float s = cw[lane] * W[lane * HH + k] + cw[lane + 64] * W[(lane + 64) * HH + k];
#pragma unroll
        for (int m = 32; m > 0; m >>= 1) s += __shfl_xor(s, m, 64);
        if (lane == 0) {
            if (prm == 0) p.az[k] = s;
            else if (prm == 1) p.bz[k] = s + p.lbz[k];
            else if (prm == 2) p.ah[k] = s;
            else p.bh[k] = s + p.lbh[k];
        }
    } else if (task == 512) {
        float av = (lane < PP) ? p.att[lane] : -1e30f;
        float m = av;
#pragma unroll
        for (int mk = 8; mk > 0; mk >>= 1) m = fmaxf(m, __shfl_xor(m, mk, 64));
        float ev = (lane < PP) ? __expf(av - m) : 0.f;
        float ssum = ev;
#pragma unroll
        for (int mk = 8; mk > 0; mk >>= 1) ssum += __shfl_xor(ssum, mk, 64);
        if (lane < PP) p.probs[lane] = ev * fast_rcp(ssum);
    }
}

__device__ __forceinline__ void prep_node(const Params& p, int node, int lane) {
    int len = min(p.cursor[node], CAP);
    int base = node * CAP;
    float s = 0.f;
    for (int i = lane; i < len; i += 64) s += __int_as_float(p.bucket[base + i].y);
#pragma unroll
    for (int m = 32; m > 0; m >>= 1) s += __shfl_xor(s, m, 64);
    float dv = fast_rsq(1.0f + s);              // +1 = self-loop weight
    if (lane == 0) p.dinv[node] = dv;
    if (lane < PP) p.y[node * PP + lane] = dv * p.x[node * PP + lane];
}

struct TailRegs {
    float prr[PP], wo0[PP], wo1[PP], bo[PP];
    float az0, bz0, ah0, bh0, az1, bz1, ah1, bh1;
};

__device__ __forceinline__ void load_tail(const Params& p, int lane, TailRegs& t) {
#pragma unroll
    for (int q = 0; q < PP; ++q) {
        t.prr[q] = p.probs[q];
        t.wo0[q] = p.Wout[lane * OO + q];
        t.wo1[q] = p.Wout[(lane + 64) * OO + q];
        t.bo[q]  = p.bout[q];
    }
    t.az0 = p.az[lane]; t.bz0 = p.bz[lane]; t.ah0 = p.ah[lane]; t.bh0 = p.bh[lane];
    t.az1 = p.az[lane + 64]; t.bz1 = p.bz[lane + 64];
    t.ah1 = p.ah[lane + 64]; t.bh1 = p.bh[lane + 64];
}

__device__ __forceinline__ void fused_node(const Params& p, const TailRegs& t,
                                           int node, int lane) {
    int len = min(p.cursor[node], CAP);
    int base = node * CAP;
    float a[PP];
#pragma unroll
    for (int q = 0; q < PP; ++q) a[q] = 0.f;
    for (int idx = lane; idx < len; idx += 64) {        // one edge per lane
        int2 sw = p.bucket[base + idx];
        float w = __int_as_float(sw.y);
        const float4* yr = (const float4*)(p.y + sw.x * PP);  // 48B rows, 16B aligned
        float4 r0 = yr[0], r1 = yr[1], r2 = yr[2];
        a[0] = fmaf(w, r0.x, a[0]); a[1] = fmaf(w, r0.y, a[1]);
        a[2] = fmaf(w, r0.z, a[2]); a[3] = fmaf(w, r0.w, a[3]);
        a[4] = fmaf(w, r1.x, a[4]); a[5] = fmaf(w, r1.y, a[5]);
        a[6] = fmaf(w, r1.z, a[6]); a[7] = fmaf(w, r1.w, a[7]);
        a[8] = fmaf(w, r2.x, a[8]); a[9] = fmaf(w, r2.y, a[9]);
        a[10] = fmaf(w, r2.z, a[10]); a[11] = fmaf(w, r2.w, a[11]);
    }
#pragma unroll
    for (int m = 32; m > 0; m >>= 1) {
#pragma unroll
        for (int q = 0; q < PP; ++q) a[q] += __shfl_xor(a[q], m, 64);
    }
    float dv_n = p.dinv[node];
    const float4* ys = (const float4*)(p.y + node * PP);
    float4 s0 = ys[0], s1 = ys[1], s2 = ys[2];          // self-loop: + y[node]
    float g[PP];
    g[0] = dv_n * (a[0] + s0.x); g[1] = dv_n * (a[1] + s0.y);
    g[2] = dv_n * (a[2] + s0.z); g[3] = dv_n * (a[3] + s0.w);
    g[4] = dv_n * (a[4] + s1.x); g[5] = dv_n * (a[5] + s1.y);
    g[6] = dv_n * (a[6] + s1.z); g[7] = dv_n * (a[7] + s1.w);
    g[8] = dv_n * (a[8] + s2.x); g[9] = dv_n * (a[9] + s2.y);
    g[10] = dv_n * (a[10] + s2.z); g[11] = dv_n * (a[11] + s2.w);
    float h0 = 0.f, h1 = 0.f;
#pragma unroll
    for (int q = 0; q < PP; ++q) {
        float gg = g[q], pr = t.prr[q];
        float o0 = fast_rcp(1.f + __expf(fmaf(gg, t.az0, t.bz0)));       // 1 - sigmoid
        float v0 = fminf(fmaxf(fmaf(gg, t.ah0, t.bh0), -15.f), 15.f);
        float t0 = 1.f - 2.f * fast_rcp(__expf(2.f * v0) + 1.f);         // tanh
        h0 = fmaf(pr * o0, t0, h0);
        float o1 = fast_rcp(1.f + __expf(fmaf(gg, t.az1, t.bz1)));
        float v1 = fminf(fmaxf(fmaf(gg, t.ah1, t.bh1), -15.f), 15.f);
        float t1 = 1.f - 2.f * fast_rcp(__expf(2.f * v1) + 1.f);
        h1 = fmaf(pr * o1, t1, h1);
    }
    h0 = h0 > 0.f ? h0 : __expf(h0) - 1.f;              // elu, alpha=1
    h1 = h1 > 0.f ? h1 : __expf(h1) - 1.f;
    float part[OO];
#pragma unroll
    for (int q = 0; q < OO; ++q) part[q] = fmaf(h0, t.wo0[q], h1 * t.wo1[q]);
#pragma unroll
    for (int m = 32; m > 0; m >>= 1) {
#pragma unroll
        for (int q = 0; q < OO; ++q) part[q] += __shfl_xor(part[q], m, 64);
    }
    if (lane == 0) {
#pragma unroll
        for (int q = 0; q < OO; ++q) p.out[node * OO + q] = part[q] + t.bo[q];
    }
}

// ---- mono-kernel cooperative path ----
__global__ void __launch_bounds__(NTHR, 2) k_all(Params p) {
    cg::grid_group grid = cg::this_grid();
    const int nthreads = gridDim.x * NTHR;
    const int gtid = blockIdx.x * NTHR + threadIdx.x;
    const int lane = threadIdx.x & 63;
    const int wid = gtid >> 6;
    const int nwaves = nthreads >> 6;

    // phase 0: zero cursors; weight-fold + probs (grid-stride over 513 wave-tasks)
    for (int i = gtid; i < p.N; i += nthreads) p.cursor[i] = 0;
    for (int task = wid; task <= 512; task += nwaves) fold_task(p, task, lane);
    __threadfence();
    grid.sync();

    // phase 1: bucket fill (1 atomic/edge)
    for (int i = gtid; i < p.E; i += nthreads) {
        int d = p.dstv[i];
        int pos = atomicAdd(&p.cursor[d], 1);
        if (pos < CAP) p.bucket[d * CAP + pos] = make_int2(p.srcv[i], __float_as_int(p.ew[i]));
    }
    __threadfence();
    grid.sync();

    // phase 2: wave-per-node deg -> dinv, y = dinv * x
    for (int node = wid; node < p.N; node += nwaves) prep_node(p, node, lane);
    __threadfence();
    grid.sync();

    // phase 3: wave-per-node fused gather + gates + attention + elu + matvec
    TailRegs t;
    load_tail(p, lane, t);
    for (int node = wid; node < p.N; node += nwaves) fused_node(p, t, node, lane);
}

// ---- multi-kernel fallback (proven R6 structure) ----
__device__ __forceinline__ void precompute_body_serial(int k, const Params& p) {
    float sz = 0.f, tz = 0.f, sh = 0.f, th = 0.f;
    for (int h = 0; h < HH; ++h) {
        float wz = p.Wz[h * HH + k];
        float wh = p.Wh[h * HH + k];
        sz += p.cwz[h] * wz; tz += p.cbz[h] * wz;
        sh += p.cwh[h] * wh; th += p.cbh[h] * wh;
    }
    p.az[k] = sz; p.bz[k] = tz + p.lbz[k]; p.ah[k] = sh; p.bh[k] = th + p.lbh[k];
    if (k == 0) {
        float m = -1e30f;
        for (int q = 0; q < PP; ++q) m = fmaxf(m, p.att[q]);
        float e[PP], ssum = 0.f;
        for (int q = 0; q < PP; ++q) { e[q] = __expf(p.att[q] - m); ssum += e[q]; }
        float inv = 1.0f / ssum;
        for (int q = 0; q < PP; ++q) p.probs[q] = e[q] * inv;
    }
}

__global__ void k_fill_b(Params p) {
    if (blockIdx.x == gridDim.x - 1) {
        if (threadIdx.x < HH) precompute_body_serial(threadIdx.x, p);
        return;
    }
    int i = blockIdx.x * blockDim.x + threadIdx.x;
    if (i >= p.E) return;
    int d = p.dstv[i];
    int pos = atomicAdd(&p.cursor[d], 1);
    if (pos < CAP) p.bucket[d * CAP + pos] = make_int2(p.srcv[i], __float_as_int(p.ew[i]));
}

__global__ void __launch_bounds__(256) k_prep_b(Params p) {
    int node = (blockIdx.x * blockDim.x + threadIdx.x) >> 6;
    int lane = threadIdx.x & 63;
    if (node < p.N) prep_node(p, node, lane);
}

__global__ void __launch_bounds__(256) k_fused_b(Params p) {
    int node = (blockIdx.x * blockDim.x + threadIdx.x) >> 6;
    int lane = threadIdx.x & 63;
    if (node >= p.N) return;
    TailRegs t;
    load_tail(p, lane, t);
    fused_node(p, t, node, lane);
}

extern "C" void kernel_launch(void* const* d_in, const int* in_sizes, int n_in,
                              void* d_out, int out_size, void* d_ws, size_t ws_size,
                              hipStream_t stream) {
    const int E = in_sizes[2];
    const int N = in_sizes[0] / PP;

    Params p;
    p.x    = (const float*)d_in[0];
    p.srcv = (const int*)d_in[1];
    p.dstv = (const int*)d_in[1] + E;
    p.ew   = (const float*)d_in[2];
    p.att  = (const float*)d_in[3];
    p.cwz  = (const float*)d_in[4];
    p.cbz  = (const float*)d_in[5];
    p.Wz   = (const float*)d_in[6];
    p.lbz  = (const float*)d_in[7];
    p.cwh  = (const float*)d_in[12];
    p.cbh  = (const float*)d_in[13];
    p.Wh   = (const float*)d_in[14];
    p.lbh  = (const float*)d_in[15];
    p.Wout = (const float*)d_in[16];
    p.bout = (const float*)d_in[17];
    p.out  = (float*)d_out;
    p.N = N; p.E = E;

    char* wsb = (char*)d_ws;
    size_t bucket_bytes = (size_t)N * CAP * sizeof(int2);   // %16 == 0
    p.bucket = (int2*)wsb;
    p.cursor = (int*)(wsb + bucket_bytes);
    p.dinv   = (float*)(p.cursor + N);
    p.y      = p.dinv + N;                                  // stays 16B aligned
    p.az     = p.y + (size_t)N * PP;
    p.bz     = p.az + HH;
    p.ah     = p.bz + HH;
    p.bh     = p.ah + HH;
    p.probs  = p.bh + HH;

    // grid sized from the runtime's own occupancy answer (capture-safe query)
    int blk_per_cu = 0;
    hipError_t qerr = hipOccupancyMaxActiveBlocksPerMultiprocessor(
        &blk_per_cu, (const void*)k_all, NTHR, 0);
    hipError_t lerr = hipErrorUnknown;
    if (qerr == hipSuccess && blk_per_cu >= 1) {
        int grid = blk_per_cu * 256;           // 256 CUs on MI355X
        if (grid > 1024) grid = 1024;
        void* args[] = {&p};
        lerr = hipLaunchCooperativeKernel((const void*)k_all, dim3(grid), dim3(NTHR),
                                          args, 0, stream);
    }
    if (lerr != hipSuccess) {
        // fallback: proven R6 multi-kernel bucket pipeline
        hipMemsetAsync(p.cursor, 0, (size_t)N * sizeof(int), stream);
        k_fill_b<<<(E + 255) / 256 + 1, 256, 0, stream>>>(p);
        k_prep_b<<<((long)N * 64 + 255) / 256, 256, 0, stream>>>(p);
        k_fused_b<<<((long)N * 64 + 255) / 256, 256, 0, stream>>>(p);
    }
}